// Round 1
// baseline (562.870 us; speedup 1.0000x reference)
//
#include <hip/hip_runtime.h>

#define FF 512
#define LL 12288
#define NJC 1556   // XB chunk count: max jc touched = 1553 (incl. K-roundup + prefetch)
#define NR 128     // XB rows = 16 shifts x 8 batches

typedef _Float16 half8 __attribute__((ext_vector_type(8)));
typedef float    f32x16 __attribute__((ext_vector_type(16)));

// ---------------- Prologue 1: kernel fp32 -> f16, 32x32x16 MFMA-A-fragment tiled
// Chunk (fgt, kc, lane): elem_i = kernel[fgt*32 + (lane&31)][kc*16 + (lane>>5)*8 + i]
__global__ __launch_bounds__(256) void build_At(const float* __restrict__ kern,
                                                _Float16* __restrict__ At) {
    int tid  = blockIdx.x * 256 + threadIdx.x;      // 786432 = 512*12288/8
    int lane = tid & 63;
    int rest = tid >> 6;                            // fgt*768 + kc
    int kc   = rest % 768;
    int fgt  = rest / 768;
    int f    = fgt * 32 + (lane & 31);
    int d0   = kc * 16 + (lane >> 5) * 8;
    const float* src = kern + (size_t)f * LL + d0;
    half8 v;
#pragma unroll
    for (int i = 0; i < 8; ++i) v[i] = (_Float16)src[i];
    ((half8*)At)[tid] = v;
}

// ---------------- Prologue 2: B chunk-major layout (UNCHANGED) ----------------
// XB[jc][r] (16B chunks): r = s*8 + b, s in [0,16). elem_i = x_b[LL-1-(8jc+i)-s]
// (zero when index < 0 -> causal mask, incl. the whole jc >= 1536 pad tail).
__global__ __launch_bounds__(256) void build_XB(const int* __restrict__ ex,
                                                _Float16* __restrict__ XB) {
    int tid = blockIdx.x * 256 + threadIdx.x;       // 199168 = NJC*NR
    if (tid >= NJC * NR) return;
    int r  = tid & 127;
    int jc = tid >> 7;
    int s  = r >> 3, b = r & 7;
    int j0 = jc * 8;
    half8 v;
#pragma unroll
    for (int i = 0; i < 8; ++i) {
        int idx = LL - 1 - (j0 + i) - s;
        float x = 0.f;
        if (idx >= 0) x = (float)ex[b * LL + idx] * 0.5f - 1.0f;
        v[i] = (_Float16)x;
    }
    ((half8*)XB)[tid] = v;
}

// ---------------- Prologue 3: out = dense_b broadcast ----------------------
__global__ __launch_bounds__(256) void init_out(const float* __restrict__ db,
                                                float* __restrict__ out) {
    int tid = blockIdx.x * 256 + threadIdx.x;       // 393216
    out[tid] = db[tid & 3];
}

__device__ __forceinline__ void gl_lds16(const half8* g, half8* l) {
    __builtin_amdgcn_global_load_lds((const __attribute__((address_space(1))) void*)g,
                                     (__attribute__((address_space(3))) void*)l, 16, 0, 0);
}

// ---------------- Main: A via LDS (BK=128 macro-steps), B register-direct --
// Block 128f x 256cols (8b x 32n), 4 waves in 2f x 2col grid, wave tile
// 64f x 128col = 2x4 mfma_32x32x16_f16 (acc 2x4x16 = 128 f32).
// One barrier per 8 K16 sub-steps: 32KB A tile double-buffered (64KB LDS).
// K rounded up to x8 kc; tail MFMAs multiply by XB's zero pad (causal mask).
__global__ __launch_bounds__(256, 2) void conv_main(const _Float16* __restrict__ At,
                                                    const _Float16* __restrict__ XB,
                                                    const float* __restrict__ bias,
                                                    const float* __restrict__ dw,
                                                    float* __restrict__ out) {
    __shared__ half8 Abuf[2][8][4][64];   // 64 KB: [buf][kc][ftile][lane]

    int bx    = blockIdx.x;
    int slot  = bx & 7;                // XCD pin: f_blk per XCD pair for L2 reuse
    int f_blk = slot >> 1;             // [0,4)
    int n_blk = 383 - ((bx >> 3) * 2 + (slot & 1));   // largest K first
    int n0 = n_blk << 5;
    int M  = (n_blk + 4) >> 2;         // ceil((n_blk+1)/4) macro (BK=128) steps

    int tid  = threadIdx.x;
    int lane = tid & 63;
    int wid  = tid >> 6;
    int wf   = wid >> 1;               // f-half of block (64 f)
    int wc   = wid & 1;                // col-half of block (16 n)
    int bb   = lane & 7;               // batch
    int nq   = (lane >> 3) & 3;        // n within 4-col group
    int kh   = lane >> 5;              // K-half within kc16

    // A staging: wave wid stages kc_local {2wid, 2wid+1} x ft {0..3}; 1KB/load.
    const half8* Ag = (const half8*)At;
    const half8* ag[8];
#pragma unroll
    for (int u = 0; u < 8; ++u) {
        int kcl = wid * 2 + (u >> 2);
        int ft  = u & 3;
        ag[u] = Ag + ((size_t)(f_blk * 4 + ft) * 768 + kcl) * 64 + lane;
    }

    // B pointers (half8 units): element_i at [jc*128 + s*8 + bb] = x_bb[LL-1-8jc-s-i].
    // Need x_bb[n - (16*kc + 8*kh + i)]  ->  8*jc + s = LL-1 - n + 8*kh + 16*kc.
    const half8* Bg = (const half8*)XB;
    const half8* pB[4];
#pragma unroll
    for (int cf = 0; cf < 4; ++cf) {
        int n  = n0 + wc * 16 + cf * 4 + nq;
        int T  = LL - 1 - n + 8 * kh;
        pB[cf] = Bg + (size_t)(T >> 3) * 128 + (T & 7) * 8 + bb;
    }

    f32x16 acc[2][4];
#pragma unroll
    for (int rf = 0; rf < 2; ++rf)
#pragma unroll
        for (int cf = 0; cf < 4; ++cf)
#pragma unroll
            for (int i = 0; i < 16; ++i) acc[rf][cf][i] = 0.f;

    // prologue: stage macro 0 -> buf0, load B(kc=0)
#pragma unroll
    for (int u = 0; u < 8; ++u)
        gl_lds16(ag[u], &Abuf[0][wid * 2 + (u >> 2)][u & 3][lane]);
    half8 bcur[4], bnxt[4];
#pragma unroll
    for (int cf = 0; cf < 4; ++cf) bcur[cf] = pB[cf][0];
#pragma unroll
    for (int cf = 0; cf < 4; ++cf) pB[cf] += 256;     // advance one kc16
    __syncthreads();

    for (int mc = 0; mc < M; ++mc) {
        int buf = mc & 1;
        if (mc + 1 < M) {
            size_t oa = (size_t)(mc + 1) * 512;       // 8 kc x 64 chunks
#pragma unroll
            for (int u = 0; u < 8; ++u)
                gl_lds16(ag[u] + oa, &Abuf[buf ^ 1][wid * 2 + (u >> 2)][u & 3][lane]);
        }
#pragma unroll
        for (int kc = 0; kc < 8; ++kc) {
#pragma unroll
            for (int cf = 0; cf < 4; ++cf) bnxt[cf] = pB[cf][0];
#pragma unroll
            for (int cf = 0; cf < 4; ++cf) pB[cf] += 256;
            half8 a0 = Abuf[buf][kc][wf * 2 + 0][lane];
            half8 a1 = Abuf[buf][kc][wf * 2 + 1][lane];
#pragma unroll
            for (int cf = 0; cf < 4; ++cf)
                acc[0][cf] = __builtin_amdgcn_mfma_f32_32x32x16_f16(a0, bcur[cf], acc[0][cf], 0, 0, 0);
#pragma unroll
            for (int cf = 0; cf < 4; ++cf)
                acc[1][cf] = __builtin_amdgcn_mfma_f32_32x32x16_f16(a1, bcur[cf], acc[1][cf], 0, 0, 0);
#pragma unroll
            for (int cf = 0; cf < 4; ++cf) bcur[cf] = bnxt[cf];
        }
        __syncthreads();
    }

    // Epilogue: bias + relu + dense over this wave's 64 f rows.
    // C/D layout (32x32): col = lane&31 = nq*8+bb, row = (reg&3)+8*(reg>>2)+4*kh.
    float p[4][4];
#pragma unroll
    for (int cf = 0; cf < 4; ++cf)
#pragma unroll
        for (int c = 0; c < 4; ++c) p[cf][c] = 0.f;

#pragma unroll
    for (int rf = 0; rf < 2; ++rf) {
#pragma unroll
        for (int reg = 0; reg < 16; ++reg) {
            int f = f_blk * 128 + wf * 64 + rf * 32 + (reg & 3) + 8 * (reg >> 2) + 4 * kh;
            float bs = bias[f];
            float4 w = *(const float4*)(dw + (size_t)f * 4);
#pragma unroll
            for (int cf = 0; cf < 4; ++cf) {
                float y = fmaxf(acc[rf][cf][reg] + bs, 0.f);
                p[cf][0] += y * w.x; p[cf][1] += y * w.y;
                p[cf][2] += y * w.z; p[cf][3] += y * w.w;
            }
        }
    }
    // reduce the two K-half lane groups (rows f+4k vs rows covered by lane^32)
#pragma unroll
    for (int cf = 0; cf < 4; ++cf)
#pragma unroll
        for (int c = 0; c < 4; ++c)
            p[cf][c] += __shfl_xor(p[cf][c], 32, 64);
    if (kh == 0) {
#pragma unroll
        for (int cf = 0; cf < 4; ++cf) {
            int n = n0 + wc * 16 + cf * 4 + nq;
            float* o = out + ((size_t)bb * LL + n) * 4;
#pragma unroll
            for (int c = 0; c < 4; ++c) atomicAdd(o + c, p[cf][c]);
        }
    }
}

extern "C" void kernel_launch(void* const* d_in, const int* in_sizes, int n_in,
                              void* d_out, int out_size, void* d_ws, size_t ws_size,
                              hipStream_t stream) {
    const int*   ex   = (const int*)d_in[0];
    const float* kern = (const float*)d_in[1];
    const float* bias = (const float*)d_in[2];
    const float* dw   = (const float*)d_in[3];
    const float* db   = (const float*)d_in[4];
    float* out = (float*)d_out;

    _Float16* At = (_Float16*)d_ws;                                   // 12.58 MB
    _Float16* XB = (_Float16*)((char*)d_ws + (size_t)FF * LL * 2);    // +3.05 MB

    hipLaunchKernelGGL(build_At, dim3(3072), dim3(256), 0, stream, kern, At);
    hipLaunchKernelGGL(build_XB, dim3(778),  dim3(256), 0, stream, ex, XB);
    hipLaunchKernelGGL(init_out, dim3(1536), dim3(256), 0, stream, db, out);
    hipLaunchKernelGGL(conv_main, dim3(1536), dim3(256), 0, stream, At, XB, bias, dw, out);
}

// Round 2
// 534.465 us; speedup vs baseline: 1.0531x; 1.0531x over previous
//
#include <hip/hip_runtime.h>

#define FF 512
#define LL 12288
#define NJC 1556   // XB chunk count: max jc touched = 1554 (incl. K-roundup + 2-deep prefetch)
#define NR 128     // XB rows = 16 shifts x 8 batches

typedef _Float16 half8 __attribute__((ext_vector_type(8)));
typedef float    f32x16 __attribute__((ext_vector_type(16)));

// ---------------- Prologue 1: kernel fp32 -> f16, 32x32x16 MFMA-A-fragment tiled
// Chunk (fgt, kc, lane): elem_i = kernel[fgt*32 + (lane&31)][kc*16 + (lane>>5)*8 + i]
__global__ __launch_bounds__(256) void build_At(const float* __restrict__ kern,
                                                _Float16* __restrict__ At) {
    int tid  = blockIdx.x * 256 + threadIdx.x;      // 786432 = 512*12288/8
    int lane = tid & 63;
    int rest = tid >> 6;                            // fgt*768 + kc
    int kc   = rest % 768;
    int fgt  = rest / 768;
    int f    = fgt * 32 + (lane & 31);
    int d0   = kc * 16 + (lane >> 5) * 8;
    const float* src = kern + (size_t)f * LL + d0;
    half8 v;
#pragma unroll
    for (int i = 0; i < 8; ++i) v[i] = (_Float16)src[i];
    ((half8*)At)[tid] = v;
}

// ---------------- Prologue 2: B chunk-major layout (UNCHANGED) ----------------
// XB[jc][r] (16B chunks): r = s*8 + b, s in [0,16). elem_i = x_b[LL-1-(8jc+i)-s]
// (zero when index < 0 -> causal mask, incl. the whole jc >= 1536 pad tail).
__global__ __launch_bounds__(256) void build_XB(const int* __restrict__ ex,
                                                _Float16* __restrict__ XB) {
    int tid = blockIdx.x * 256 + threadIdx.x;       // 199168 = NJC*NR
    if (tid >= NJC * NR) return;
    int r  = tid & 127;
    int jc = tid >> 7;
    int s  = r >> 3, b = r & 7;
    int j0 = jc * 8;
    half8 v;
#pragma unroll
    for (int i = 0; i < 8; ++i) {
        int idx = LL - 1 - (j0 + i) - s;
        float x = 0.f;
        if (idx >= 0) x = (float)ex[b * LL + idx] * 0.5f - 1.0f;
        v[i] = (_Float16)x;
    }
    ((half8*)XB)[tid] = v;
}

// ---------------- Prologue 3: out = dense_b broadcast ----------------------
__global__ __launch_bounds__(256) void init_out(const float* __restrict__ db,
                                                float* __restrict__ out) {
    int tid = blockIdx.x * 256 + threadIdx.x;       // 393216
    out[tid] = db[tid & 3];
}

__device__ __forceinline__ void gl_lds16(const half8* g, half8* l) {
    __builtin_amdgcn_global_load_lds((const __attribute__((address_space(1))) void*)g,
                                     (__attribute__((address_space(3))) void*)l, 16, 0, 0);
}

// ---------------- Main: A via LDS (BK=128 macro-steps), B register-direct --
// Block 128f x 256cols (8b x 32n), 4 waves each owning 128f x 64col
// (8 positions x 8 batches): 4x2 mfma_32x32x16_f16 per kc16 (acc 4x2x16).
// Single B coverage (each B fragment loaded by exactly one wave), 2-deep
// B prefetch. One barrier per 8 kc16 sub-steps; 32KB A tile double-buffered.
// K rounded up to x8 kc; tail MFMAs multiply by XB's zero pad (causal mask).
__global__ __launch_bounds__(256, 2) void conv_main(const _Float16* __restrict__ At,
                                                    const _Float16* __restrict__ XB,
                                                    const float* __restrict__ bias,
                                                    const float* __restrict__ dw,
                                                    float* __restrict__ out) {
    __shared__ half8 Abuf[2][8][4][64];   // 64 KB: [buf][kc][ftile][lane]

    int bx    = blockIdx.x;
    int slot  = bx & 7;                // XCD pin: f_blk per XCD pair for L2 reuse
    int f_blk = slot >> 1;             // [0,4)
    int n_blk = 383 - ((bx >> 3) * 2 + (slot & 1));   // largest K first
    int n0 = n_blk << 5;
    int M  = (n_blk + 4) >> 2;         // ceil((n_blk+1)/4) macro (BK=128) steps

    int tid  = threadIdx.x;
    int lane = tid & 63;
    int wid  = tid >> 6;
    int bb   = lane & 7;               // batch
    int nq   = (lane >> 3) & 3;        // position within 4-col group
    int kh   = lane >> 5;              // K-half within kc16

    // A staging: wave wid stages kc_local {2wid, 2wid+1} x ft {0..3}; 1KB/load.
    const half8* Ag = (const half8*)At;
    const half8* ag[8];
#pragma unroll
    for (int u = 0; u < 8; ++u) {
        int kcl = wid * 2 + (u >> 2);
        int ft  = u & 3;
        ag[u] = Ag + ((size_t)(f_blk * 4 + ft) * 768 + kcl) * 64 + lane;
    }

    // B pointers (half8 units): element_i at [jc*128 + s*8 + bb] = x_bb[LL-1-8jc-s-i].
    // Need x_bb[n - (16*kc + 8*kh + i)]  ->  8*jc + s = LL-1 - n + 8*kh + 16*kc.
    const half8* Bg = (const half8*)XB;
    const half8* pB[2];
#pragma unroll
    for (int cf = 0; cf < 2; ++cf) {
        int n  = n0 + wid * 8 + cf * 4 + nq;
        int T  = LL - 1 - n + 8 * kh;
        pB[cf] = Bg + (size_t)(T >> 3) * 128 + (T & 7) * 8 + bb;
    }

    f32x16 acc[4][2];
#pragma unroll
    for (int rf = 0; rf < 4; ++rf)
#pragma unroll
        for (int cf = 0; cf < 2; ++cf)
#pragma unroll
            for (int i = 0; i < 16; ++i) acc[rf][cf][i] = 0.f;

    // prologue: stage macro 0 -> buf0, load B(kc=0) and B(kc=1)
#pragma unroll
    for (int u = 0; u < 8; ++u)
        gl_lds16(ag[u], &Abuf[0][wid * 2 + (u >> 2)][u & 3][lane]);
    half8 b0[2], b1[2], b2[2];
#pragma unroll
    for (int cf = 0; cf < 2; ++cf) {
        b0[cf] = pB[cf][0];
        b1[cf] = pB[cf][256];
        pB[cf] += 512;                 // now points at kc-step 2
    }
    __syncthreads();

    for (int mc = 0; mc < M; ++mc) {
        int buf = mc & 1;
        if (mc + 1 < M) {
            size_t oa = (size_t)(mc + 1) * 512;       // 8 kc x 64 chunks
#pragma unroll
            for (int u = 0; u < 8; ++u)
                gl_lds16(ag[u] + oa, &Abuf[buf ^ 1][wid * 2 + (u >> 2)][u & 3][lane]);
        }
#pragma unroll
        for (int kc = 0; kc < 8; ++kc) {
#pragma unroll
            for (int cf = 0; cf < 2; ++cf) { b2[cf] = pB[cf][0]; pB[cf] += 256; }
            half8 a[4];
#pragma unroll
            for (int rf = 0; rf < 4; ++rf) a[rf] = Abuf[buf][kc][rf][lane];
#pragma unroll
            for (int rf = 0; rf < 4; ++rf)
#pragma unroll
                for (int cf = 0; cf < 2; ++cf)
                    acc[rf][cf] = __builtin_amdgcn_mfma_f32_32x32x16_f16(a[rf], b0[cf], acc[rf][cf], 0, 0, 0);
#pragma unroll
            for (int cf = 0; cf < 2; ++cf) { b0[cf] = b1[cf]; b1[cf] = b2[cf]; }
        }
        __syncthreads();
    }

    // Epilogue: bias + relu + dense over all 128 f rows of the block.
    // C/D layout (32x32): col = lane&31 = nq*8+bb, row = (reg&3)+8*(reg>>2)+4*kh.
    float p[2][4];
#pragma unroll
    for (int cf = 0; cf < 2; ++cf)
#pragma unroll
        for (int c = 0; c < 4; ++c) p[cf][c] = 0.f;

#pragma unroll
    for (int rf = 0; rf < 4; ++rf) {
#pragma unroll
        for (int reg = 0; reg < 16; ++reg) {
            int f = f_blk * 128 + rf * 32 + (reg & 3) + 8 * (reg >> 2) + 4 * kh;
            float bs = bias[f];
            float4 w = *(const float4*)(dw + (size_t)f * 4);
#pragma unroll
            for (int cf = 0; cf < 2; ++cf) {
                float y = fmaxf(acc[rf][cf][reg] + bs, 0.f);
                p[cf][0] += y * w.x; p[cf][1] += y * w.y;
                p[cf][2] += y * w.z; p[cf][3] += y * w.w;
            }
        }
    }
    // combine the two K-half lane groups (same col, disjoint f rows)
#pragma unroll
    for (int cf = 0; cf < 2; ++cf)
#pragma unroll
        for (int c = 0; c < 4; ++c)
            p[cf][c] += __shfl_xor(p[cf][c], 32, 64);
    if (kh == 0) {
#pragma unroll
        for (int cf = 0; cf < 2; ++cf) {
            int n = n0 + wid * 8 + cf * 4 + nq;
            float* o = out + ((size_t)bb * LL + n) * 4;
#pragma unroll
            for (int c = 0; c < 4; ++c) atomicAdd(o + c, p[cf][c]);
        }
    }
}

extern "C" void kernel_launch(void* const* d_in, const int* in_sizes, int n_in,
                              void* d_out, int out_size, void* d_ws, size_t ws_size,
                              hipStream_t stream) {
    const int*   ex   = (const int*)d_in[0];
    const float* kern = (const float*)d_in[1];
    const float* bias = (const float*)d_in[2];
    const float* dw   = (const float*)d_in[3];
    const float* db   = (const float*)d_in[4];
    float* out = (float*)d_out;

    _Float16* At = (_Float16*)d_ws;                                   // 12.58 MB
    _Float16* XB = (_Float16*)((char*)d_ws + (size_t)FF * LL * 2);    // +3.05 MB

    hipLaunchKernelGGL(build_At, dim3(3072), dim3(256), 0, stream, kern, At);
    hipLaunchKernelGGL(build_XB, dim3(778),  dim3(256), 0, stream, ex, XB);
    hipLaunchKernelGGL(init_out, dim3(1536), dim3(256), 0, stream, db, out);
    hipLaunchKernelGGL(conv_main, dim3(1536), dim3(256), 0, stream, At, XB, bias, dw, out);
}